// Round 12
// baseline (3829.488 us; speedup 1.0000x reference)
//
#include <hip/hip_runtime.h>
#include <hip/hip_bf16.h>

typedef __attribute__((ext_vector_type(4))) float fx4;
typedef __attribute__((ext_vector_type(8))) short bf8;   // 8 x bf16
typedef __attribute__((ext_vector_type(4))) short sx4;   // 4 x bf16
typedef __attribute__((ext_vector_type(4))) int ix4;

#define NBLK 96          // 3 layers x 32 blocks
#define HSZ (32 * 512)   // one h plane (batch x hidden) in shorts

__device__ __forceinline__ short f2bf(float f) {
  __hip_bfloat16 h = __float2bfloat16(f);
  return *reinterpret_cast<short*>(&h);
}
__device__ __forceinline__ float bf2f(short s) {
  union { unsigned u; float f; } c; c.u = ((unsigned)(unsigned short)s) << 16; return c.f;
}
__device__ __forceinline__ float rcpf(float x) { return __builtin_amdgcn_rcpf(x); }
__device__ __forceinline__ bf8 asbf8(ix4 v) { union { ix4 i; bf8 b; } u; u.i = v; return u.b; }

// LLC-coherent (cross-XCD) 16B load
#define LDH(dst, p, OFF) \
  asm volatile("global_load_dwordx4 %0, %1, off offset:" OFF " sc0 sc1" \
               : "=v"(dst) : "v"(p) : "memory")
// plain cached 16B load (static data: x)
#define LDP(dst, p, OFF) \
  asm volatile("global_load_dwordx4 %0, %1, off offset:" OFF \
               : "=v"(dst) : "v"(p) : "memory")
#define LD8(OP, A, P) do { \
  OP(A[0], P, "0");   OP(A[1], P, "64");  OP(A[2], P, "128"); OP(A[3], P, "192"); \
  OP(A[4], P, "256"); OP(A[5], P, "320"); OP(A[6], P, "384"); OP(A[7], P, "448"); } while (0)
// coherent dword store / self-waiting poll load
#define ST4_C(p, v) \
  asm volatile("global_store_dword %0, %1, off sc0 sc1" :: "v"(p), "v"(v) : "memory")
#define LD4_C(d, p) \
  asm volatile("global_load_dword %0, %1, off sc0 sc1\n\ts_waitcnt vmcnt(0)" \
               : "=v"(d) : "v"(p) : "memory")

// x (B=32,T=512,D=256) fp32 -> xt (T,B,256) bf16 hi+lo (rows = t*32+b)
__global__ __launch_bounds__(256) void conv_x_k(const float* __restrict__ x,
                                                short* __restrict__ xhi, short* __restrict__ xlo) {
  int i = blockIdx.x * 256 + threadIdx.x;
  fx4 v = *(const fx4*)(x + (size_t)i * 4);
  int k = (i * 4) & 255;
  int row = (i * 4) >> 8;                            // b*512 + t
  int b = row >> 9, t = row & 511;
  sx4 hi, lo;
#pragma unroll
  for (int e = 0; e < 4; ++e) {
    hi[e] = f2bf(v[e]);
    lo[e] = f2bf(v[e] - bf2f(hi[e]));
  }
  size_t o = ((size_t)(t * 32 + b)) * 256 + k;
  *(sx4*)(xhi + o) = hi;
  *(sx4*)(xlo + o) = lo;
}

// Whole-wave gate on 32 PACKED flags (2 cache lines): lane i polls flag i,
// ballot joins. 2 LLC transactions per poll iteration (vs 32 scalar spins).
__device__ __forceinline__ void gate_wave(const int* flags, int base, int lane, int need) {
  const int* fp = flags + base + (lane & 31);
  while (true) {
    int v; LD4_C(v, fp);
    if (__ballot(v >= need) == ~0ull) break;
    __builtin_amdgcn_s_sleep(1);
  }
}

// Per-layer body. Layer L (32 blocks); block p owns 16 output cols j0=p*16.
// h planes bf16 hi+lo; weights hi+lo in registers; 3-term MFMA (R2/R6 numerics).
//
// FLAGS (packed, flags[L*32+p]) = completed step + 3 (init 2 = "h_{-1} published").
// PER-WAVE gates at step s (waves join at the post-MFMA __syncthreads):
//   w2,w3 (h2h):       own-layer  flags >= s+2  (h_{L,s-1} readable)
//   w0,w1 (inW, L>0):  prev-layer flags >= s+3  (h_{L-1,s} readable)
//   w0,w1 (L<2):       next-layer flags >= s    (plane s%3 consumed -> writable)
// hg per layer: [buf 3][hi/lo 2][32][512]; step s -> buf s%3.
template<int L>
__device__ __forceinline__ void rec3_body(
    float (*m_lds)[32][52], float* bias_s,
    const short* __restrict__ xth, const short* __restrict__ xtl,
    const float* __restrict__ Wi, const float* __restrict__ bi,
    const float* __restrict__ Wh, const float* __restrict__ bh,
    short* __restrict__ hgl, const short* __restrict__ hgp,
    int* flags, float* __restrict__ out, int p)
{
  const int tid = threadIdx.x;
  const int j0 = p * 16;
  const int w = tid >> 6, lane = tid & 63, lm = lane & 15, lk = lane >> 4;
  const bool inW = (w < 2);
  constexpr int KIN = (L == 0) ? 256 : 512;

  const int kbase = inW ? ((L == 0) ? 0 : w * 256) : (w - 2) * 256;
  const float* Wf = inW ? Wi : Wh;
  const int wstr = inW ? KIN : 512;

  // ---- weight slice -> register B-fragments, bf16 hi+lo (static 3x8) ----
  bf8 bwh[3][8], bwl[3][8];
#pragma unroll
  for (int g = 0; g < 3; ++g) {
    const int grow = g * 512 + j0 + lm;
#pragma unroll
    for (int ks = 0; ks < 8; ++ks) {
      const float* src = Wf + (size_t)grow * wstr + kbase + ks * 32 + lk * 8;
      fx4 f0 = *(const fx4*)(src);
      fx4 f1 = *(const fx4*)(src + 4);
      bf8 vh, vl;
#pragma unroll
      for (int e = 0; e < 4; ++e) {
        vh[e] = f2bf(f0[e]);     vl[e] = f2bf(f0[e] - bf2f(vh[e]));
        vh[4 + e] = f2bf(f1[e]); vl[4 + e] = f2bf(f1[e] - bf2f(vh[4 + e]));
      }
      bwh[g][ks] = vh; bwl[g][ks] = vl;
    }
  }
  if (tid < 48) bias_s[tid] = bi[(tid >> 4) * 512 + j0 + (tid & 15)];
  else if (tid < 96) {
    const int u = tid - 48;
    bias_s[48 + u] = bh[(u >> 4) * 512 + j0 + (u & 15)];
  }
  {  // zero own plane 2 hi+lo: h_{L,-1} = 0, read at s=0 (plane (0-1)%3 = 2)
    const int zb = tid >> 3, zc = (tid & 7) * 2;
    ST4_C((int*)(hgl + (size_t)4 * HSZ + (size_t)zb * 512 + j0 + zc), 0);
    ST4_C((int*)(hgl + (size_t)5 * HSZ + (size_t)zb * 512 + j0 + zc), 0);
  }
  asm volatile("s_waitcnt vmcnt(0)" ::: "memory");
  __syncthreads();
  if (tid == 0) ST4_C(flags + L * 32 + p, 2);

  const int cb = tid >> 3, c2 = (tid & 7) * 2;   // cell phase: (batch, 2 cols)
  float hv0 = 0.f, hv1 = 0.f;
  int bufw = 0;                                   // s % 3

  for (int s = 0; s < 512; ++s) {
    const int bufr = (bufw == 0) ? 2 : bufw - 1;  // (s-1) % 3
    ix4 rh[2][8], rl[2][8];
    if (L == 0 && inW) {   // x static — plain cached loads before any gate
      const short* xh = xth + (size_t)(s * 32 + w * 16 + lm) * 256 + lk * 8;
      const short* xl = xtl + (size_t)(s * 32 + w * 16 + lm) * 256 + lk * 8;
      LD8(LDP, rh[0], xh);
      LD8(LDP, rl[0], xl);
    }

    // ---- per-wave gates (whole-wave coalesced ballot polls) ----
    if (!inW) {
      gate_wave(flags, L * 32, lane, s + 2);               // own (critical cycle)
    } else {
      if (L > 0) gate_wave(flags, (L - 1) * 32, lane, s + 3);  // prev
      if (L < 2) gate_wave(flags, (L + 1) * 32, lane, s);      // next (slack 3)
    }

    // ---- gated h loads (hi + lo) ----
    if (inW) {
      if constexpr (L > 0) {
        const short* base = hgp + (size_t)(bufw * 2) * HSZ + (size_t)lm * 512 + kbase + lk * 8;
        LD8(LDH, rh[0], base);
        LD8(LDH, rh[1], base + 16 * 512);
        LD8(LDH, rl[0], base + HSZ);
        LD8(LDH, rl[1], base + HSZ + 16 * 512);
      }
    } else {
      const short* base = hgl + (size_t)(bufr * 2) * HSZ + (size_t)lm * 512 + kbase + lk * 8;
      LD8(LDH, rh[0], base);
      LD8(LDH, rh[1], base + 16 * 512);
      LD8(LDH, rl[0], base + HSZ);
      LD8(LDH, rl[1], base + HSZ + 16 * 512);
    }
    asm volatile("s_waitcnt vmcnt(0)" ::: "memory");
    __builtin_amdgcn_sched_barrier(0);   // rule #18

    fx4 acc[2][3];
#pragma unroll
    for (int mt = 0; mt < 2; ++mt)
#pragma unroll
      for (int g = 0; g < 3; ++g) acc[mt][g] = (fx4){0.f, 0.f, 0.f, 0.f};

    if (L == 0 && inW) {   // x hi+lo, 3-term
#pragma unroll
      for (int ks = 0; ks < 8; ++ks) {
        bf8 ah = asbf8(rh[0][ks]);
        bf8 al = asbf8(rl[0][ks]);
#pragma unroll
        for (int g = 0; g < 3; ++g) {
          acc[0][g] = __builtin_amdgcn_mfma_f32_16x16x32_bf16(ah, bwh[g][ks], acc[0][g], 0, 0, 0);
          acc[0][g] = __builtin_amdgcn_mfma_f32_16x16x32_bf16(al, bwh[g][ks], acc[0][g], 0, 0, 0);
          acc[0][g] = __builtin_amdgcn_mfma_f32_16x16x32_bf16(ah, bwl[g][ks], acc[0][g], 0, 0, 0);
        }
      }
    } else {               // h hi+lo x weight hi+lo, 3-term
#pragma unroll
      for (int ks = 0; ks < 8; ++ks) {
#pragma unroll
        for (int mt = 0; mt < 2; ++mt) {
          bf8 ah = asbf8(rh[mt][ks]);
          bf8 al = asbf8(rl[mt][ks]);
#pragma unroll
          for (int g = 0; g < 3; ++g) {
            acc[mt][g] = __builtin_amdgcn_mfma_f32_16x16x32_bf16(ah, bwh[g][ks], acc[mt][g], 0, 0, 0);
            acc[mt][g] = __builtin_amdgcn_mfma_f32_16x16x32_bf16(al, bwh[g][ks], acc[mt][g], 0, 0, 0);
            acc[mt][g] = __builtin_amdgcn_mfma_f32_16x16x32_bf16(ah, bwl[g][ks], acc[mt][g], 0, 0, 0);
          }
        }
      }
    }

    if (L == 0 && inW) {   // wave w -> rows w*16.. of partial plane 0
#pragma unroll
      for (int g = 0; g < 3; ++g)
#pragma unroll
        for (int q = 0; q < 4; ++q)
          m_lds[0][w * 16 + lk * 4 + q][g * 16 + lm] = acc[0][g][q];
    } else {
#pragma unroll
      for (int mt = 0; mt < 2; ++mt)
#pragma unroll
        for (int g = 0; g < 3; ++g)
#pragma unroll
          for (int q = 0; q < 4; ++q)
            m_lds[w][mt * 16 + lk * 4 + q][g * 16 + lm] = acc[mt][g][q];
    }
    __syncthreads();   // joins all waves; w0/w1's next-gate now covers the block

    // cell: planes 0(,1) = input partial(s), 2,3 = h2h K-halves
    float av[3][2], hh[3][2];
#pragma unroll
    for (int g = 0; g < 3; ++g)
#pragma unroll
      for (int e = 0; e < 2; ++e) {
        const int c = g * 16 + c2 + e;
        float ain = m_lds[0][cb][c];
        if (L > 0) ain += m_lds[1][cb][c];
        av[g][e] = ain + bias_s[c];
        hh[g][e] = m_lds[2][cb][c] + m_lds[3][cb][c] + bias_s[48 + c];
      }
    float hvv[2] = {hv0, hv1}, hn[2];
#pragma unroll
    for (int e = 0; e < 2; ++e) {
      float pr = av[0][e] + hh[0][e];
      float pz = av[1][e] + hh[1][e];
      float h2n = hh[2][e];
      float pn = av[2][e] + h2n;
      float sr = rcpf(1.f + __expf(-pr));  // sigmoid
      float rr = __expf(-__expf(-sr));     // Gumbel squash
      float sz = rcpf(1.f + __expf(-pz));
      float zz = __expf(-__expf(-sz));
      float na = pn + rr * h2n;
      float ex = __expf(2.f * na);         // tanh via exp
      float nn = 1.f - 2.f * rcpf(ex + 1.f);
      hn[e] = (1.f - zz) * nn + zz * hvv[e];
    }
    hv0 = hn[0]; hv1 = hn[1];
    short h0h = f2bf(hn[0]), h0l = f2bf(hn[0] - bf2f(h0h));
    short h1h = f2bf(hn[1]), h1l = f2bf(hn[1] - bf2f(h1h));
    int packh = (int)(unsigned short)h0h | ((int)(unsigned short)h1h << 16);
    int packl = (int)(unsigned short)h0l | ((int)(unsigned short)h1l << 16);

    short* hw = hgl + (size_t)(bufw * 2) * HSZ;
    ST4_C((int*)(hw + (size_t)cb * 512 + j0 + c2), packh);
    ST4_C((int*)(hw + HSZ + (size_t)cb * 512 + j0 + c2), packl);
    if (L == 2 && s == 511) {
      out[(size_t)cb * 512 + j0 + c2] = hn[0];
      out[(size_t)cb * 512 + j0 + c2 + 1] = hn[1];
    }
    asm volatile("s_waitcnt vmcnt(0)" ::: "memory");  // per-wave publish drain
    __syncthreads();                                  // all waves drained
    if (tid == 0) ST4_C(flags + L * 32 + p, s + 3);

    bufw = (bufw == 2) ? 0 : bufw + 1;
  }
}

__global__ __launch_bounds__(256, 1) void rec3(
    const short* __restrict__ xth, const short* __restrict__ xtl,
    const float* __restrict__ Wi0, const float* __restrict__ bi0,
    const float* __restrict__ Wh0, const float* __restrict__ bh0,
    const float* __restrict__ Wi1, const float* __restrict__ bi1,
    const float* __restrict__ Wh1, const float* __restrict__ bh1,
    const float* __restrict__ Wi2, const float* __restrict__ bi2,
    const float* __restrict__ Wh2, const float* __restrict__ bh2,
    short* __restrict__ hg, int* flags, float* __restrict__ out)
{
  __shared__ __align__(16) float m_lds[4][32][52];
  __shared__ float bias_s[96];
  const int bid = blockIdx.x;
  const int l = bid >> 5, p = bid & 31;
  short* hgl = hg + (size_t)l * 6 * HSZ;
  const short* hgp = (l > 0) ? (hg + (size_t)(l - 1) * 6 * HSZ) : hg;
  if (l == 0)
    rec3_body<0>(m_lds, bias_s, xth, xtl, Wi0, bi0, Wh0, bh0, hgl, hgp, flags, out, p);
  else if (l == 1)
    rec3_body<1>(m_lds, bias_s, nullptr, nullptr, Wi1, bi1, Wh1, bh1, hgl, hgp, flags, out, p);
  else
    rec3_body<2>(m_lds, bias_s, nullptr, nullptr, Wi2, bi2, Wh2, bh2, hgl, hgp, flags, out, p);
}

extern "C" void kernel_launch(void* const* d_in, const int* in_sizes, int n_in,
                              void* d_out, int out_size, void* d_ws, size_t ws_size,
                              hipStream_t stream) {
  const float* x   = (const float*)d_in[0];
  const float* Wi0 = (const float*)d_in[1];
  const float* bi0 = (const float*)d_in[2];
  const float* Wh0 = (const float*)d_in[3];
  const float* bh0 = (const float*)d_in[4];
  const float* Wi1 = (const float*)d_in[5];
  const float* bi1 = (const float*)d_in[6];
  const float* Wh1 = (const float*)d_in[7];
  const float* bh1 = (const float*)d_in[8];
  const float* Wi2 = (const float*)d_in[9];
  const float* bi2 = (const float*)d_in[10];
  const float* Wh2 = (const float*)d_in[11];
  const float* bh2 = (const float*)d_in[12];
  float* out = (float*)d_out;
  (void)in_sizes; (void)n_in; (void)out_size; (void)ws_size;

  char* ws = (char*)d_ws;
  size_t off = 0;
  auto alloc = [&](size_t b) { char* p = ws + off; off = (off + b + 255) & ~(size_t)255; return p; };
  short* xth   = (short*)alloc(16384ull * 256 * 2);   // 8.4 MB
  short* xtl   = (short*)alloc(16384ull * 256 * 2);
  short* hg    = (short*)alloc(3ull * 6 * HSZ * 2);   // 3 layers x [3buf][hi/lo][32][512]
  int*   flags = (int*)alloc(NBLK * 4);               // PACKED: 96 ints

  hipMemsetAsync(flags, 0, NBLK * 4, stream);
  hipLaunchKernelGGL(conv_x_k, dim3(4096), dim3(256), 0, stream, x, xth, xtl);
  hipLaunchKernelGGL(rec3, dim3(NBLK), dim3(256), 0, stream,
                     xth, xtl,
                     Wi0, bi0, Wh0, bh0,
                     Wi1, bi1, Wh1, bh1,
                     Wi2, bi2, Wh2, bh2,
                     hg, flags, out);
}